// Round 13
// baseline (576.262 us; speedup 1.0000x reference)
//
#include <hip/hip_runtime.h>
#include <cstddef>
#include <cstdint>

#define NNODES 8192
#define BATCH  16
#define HID    64
#define NEDGE  131072
#define SN     524288   // NNODES * HID (per-batch state stride)
#define OUTHALF 8388608 // BATCH * SN
#define FP2    72       // padded per-slab feature dim (66 real + 6 zero); 72 = 9*8
#define SLABU  1152     // ushorts per (node, slab) = 16*72
#define NSTR   5760     // ushorts per node = 5*SLABU
#define NSTR4  720      // uint4 per node in Xb (5760 ushorts / 8 per uint4)
#define XCS4   144      // uint4 per node in Xc (slab0-only buffer, 1152/8)
#define KP2    384      // padded K' = 12 k-tiles of 32 (360 real + 24 zero)
#define GN     4        // nodes per GEMM block (2048 blocks; removes r4's grid cap of 4 blk/CU)
#define CWB    288      // convert_w blocks inside prep_kernel (192*KP2/256)
#define BXB    18432    // build_x0 blocks inside prep_kernel (NNODES*BATCH*36/256)

typedef __attribute__((ext_vector_type(8))) short bf16x8;
typedef __attribute__((ext_vector_type(4))) float f32x4;

static __device__ __forceinline__ float bf2f(ushort u) {
    union { uint32_t i; float f; } c; c.i = ((uint32_t)u) << 16; return c.f;
}
static __device__ __forceinline__ ushort f2bf(float f) {
    union { float f; uint32_t i; } c; c.f = f;
    uint32_t lsb = (c.i >> 16) & 1;
    return (ushort)((c.i + 0x7fffu + lsb) >> 16);
}

// ---------------- CSR construction ----------------

__global__ void zero_counts_kernel(int* __restrict__ c1, int* __restrict__ c2) {
    int i = blockIdx.x * 256 + threadIdx.x;
    if (i < NNODES) { c1[i] = 0; c2[i] = 0; }
}

__global__ void hist_kernel(const int* __restrict__ src, const int* __restrict__ dst,
                            int* __restrict__ c1, int* __restrict__ c2) {
    int e = blockIdx.x * 256 + threadIdx.x;
    if (e < NEDGE) {
        atomicAdd(&c1[src[e]], 1);
        atomicAdd(&c2[dst[e]], 1);
    }
}

// Both CSR scans in ONE dispatch: block 0 -> graph 1, block 1 -> graph 2.
__global__ __launch_bounds__(1024) void scan_kernel(const int* __restrict__ counts1,
                                                    const int* __restrict__ counts2,
                                                    int* __restrict__ rowptr1,
                                                    int* __restrict__ rowptr2,
                                                    int* __restrict__ cursor1,
                                                    int* __restrict__ cursor2) {
    const int* counts = blockIdx.x ? counts2 : counts1;
    int* rowptr       = blockIdx.x ? rowptr2 : rowptr1;
    int* cursor       = blockIdx.x ? cursor2 : cursor1;
    __shared__ int sh[1024];
    int tid = threadIdx.x;
    int base = tid * 8;
    int local[8];
    int sum = 0;
#pragma unroll
    for (int j = 0; j < 8; ++j) { local[j] = counts[base + j]; sum += local[j]; }
    sh[tid] = sum;
    __syncthreads();
    for (int off = 1; off < 1024; off <<= 1) {
        int v = (tid >= off) ? sh[tid - off] : 0;
        __syncthreads();
        sh[tid] += v;
        __syncthreads();
    }
    int p = sh[tid] - sum;
#pragma unroll
    for (int j = 0; j < 8; ++j) {
        cursor[base + j] = p;
        p += local[j];
        rowptr[base + j + 1] = p;
    }
    if (tid == 0) rowptr[0] = 0;
}

__global__ void scatter_kernel(const int* __restrict__ src, const int* __restrict__ dst,
                               const float* __restrict__ v1, const float* __restrict__ v2,
                               int* __restrict__ cur1, int* __restrict__ cur2,
                               int* __restrict__ cols1, float* __restrict__ valsC1,
                               int* __restrict__ cols2, float* __restrict__ valsC2) {
    int e = blockIdx.x * 256 + threadIdx.x;
    if (e < NEDGE) {
        int r1 = src[e];
        int p1 = atomicAdd(&cur1[r1], 1);
        cols1[p1] = dst[e];
        valsC1[p1] = v1[e];
        int r2 = dst[e];
        int p2 = atomicAdd(&cur2[r2], 1);
        cols2[p2] = src[e];
        valsC2[p2] = v2[e];
    }
}

// -------- fused prep: convert_w (blocks [0,CWB)) + build_x0 (blocks [CWB,CWB+BXB)) --------
// convert: W[k=f*5+m][C] -> WT[C][k'=m*72+f].  build: x0 -> Xb slab0 + Xc input/pad parts.

__global__ void prep_kernel(const float* __restrict__ Wg, const float* __restrict__ Wc,
                            ushort* __restrict__ WgT, ushort* __restrict__ WcT,
                            const float* __restrict__ inputs, const float* __restrict__ state,
                            uint* __restrict__ Xb_u, uint* __restrict__ Xc_u) {
    if (blockIdx.x < CWB) {
        int i = blockIdx.x * 256 + threadIdx.x;
        if (i >= 192 * KP2) return;
        int col = i / KP2, k2 = i - col * KP2;
        int m = k2 / FP2, f = k2 - m * FP2;
        bool valid = (m < 5) && (f < 66);
        int ko = f * 5 + m;
        if (col < 128) {
            WgT[col * KP2 + k2] = valid ? f2bf(Wg[ko * 128 + col]) : (ushort)0;
        } else {
            int c = col - 128;
            WcT[c * KP2 + k2] = valid ? f2bf(Wc[ko * 64 + c]) : (ushort)0;
        }
        return;
    }
    int t = (blockIdx.x - CWB) * 256 + threadIdx.x;
    if (t >= NNODES * BATCH * 36) return;
    int n = t / 576;           // 576 = 16*36 uints per node-slab
    int r = t - n * 576;       // b*36 + j
    int b = r / 36;
    int j = r - b * 36;
    int f0 = 2 * j;
    uint val = 0;
    if (f0 == 0) {
        float v0 = inputs[(size_t)b * (NNODES * 2) + n * 2 + 0];
        float v1 = inputs[(size_t)b * (NNODES * 2) + n * 2 + 1];
        val = (uint)f2bf(v0) | ((uint)f2bf(v1) << 16);
    } else if (f0 < 66) {
        float v0 = state[(size_t)b * SN + n * HID + (f0 - 2)];
        float v1 = state[(size_t)b * SN + n * HID + (f0 - 1)];
        val = (uint)f2bf(v0) | ((uint)f2bf(v1) << 16);
    }
    Xb_u[(size_t)n * 2880 + r] = val;               // slab0 = first 576 uints of node
    if (f0 == 0 || f0 >= 66) Xc_u[t] = val;         // inputs + zero pads of xc slab0
}

// ---------------- SPMM (bf16 rows, fp32 accumulate), 8-wide PREDICATED, dual-graph ----------------
// r12 engine UNCHANGED (control): 3.3-3.7 TB/s logical gather across three
// structurally different designs (r5/r9/r12) -> gather-path plateau.

static __device__ __forceinline__ void fma8(float* acc, uint4 d, float v) {
    acc[0] += v * bf2f((ushort)(d.x));  acc[1] += v * bf2f((ushort)(d.x >> 16));
    acc[2] += v * bf2f((ushort)(d.y));  acc[3] += v * bf2f((ushort)(d.y >> 16));
    acc[4] += v * bf2f((ushort)(d.z));  acc[5] += v * bf2f((ushort)(d.z >> 16));
    acc[6] += v * bf2f((ushort)(d.w));  acc[7] += v * bf2f((ushort)(d.w >> 16));
}

static __device__ __forceinline__ uint4 blend_pack8(const float* acc, uint4 p,
                                                    float alpha, float beta) {
    float o[8];
    o[0] = alpha * acc[0] + beta * bf2f((ushort)(p.x));
    o[1] = alpha * acc[1] + beta * bf2f((ushort)(p.x >> 16));
    o[2] = alpha * acc[2] + beta * bf2f((ushort)(p.y));
    o[3] = alpha * acc[3] + beta * bf2f((ushort)(p.y >> 16));
    o[4] = alpha * acc[4] + beta * bf2f((ushort)(p.z));
    o[5] = alpha * acc[5] + beta * bf2f((ushort)(p.z >> 16));
    o[6] = alpha * acc[6] + beta * bf2f((ushort)(p.w));
    o[7] = alpha * acc[7] + beta * bf2f((ushort)(p.w >> 16));
    uint4 r;
    r.x = (uint32_t)f2bf(o[0]) | ((uint32_t)f2bf(o[1]) << 16);
    r.y = (uint32_t)f2bf(o[2]) | ((uint32_t)f2bf(o[3]) << 16);
    r.z = (uint32_t)f2bf(o[4]) | ((uint32_t)f2bf(o[5]) << 16);
    r.w = (uint32_t)f2bf(o[6]) | ((uint32_t)f2bf(o[7]) << 16);
    return r;
}

// row = 144 uint4 (2304 B) per (node, slab). strides in uint4 units.
// blocks [0,8192): graph 1; [8192,16384): graph 2. Both halves share xp/alpha/beta.
__global__ __launch_bounds__(128) void spmm_dual(
        const int* __restrict__ rp1, const int* __restrict__ c1, const float* __restrict__ v1,
        const uint4* __restrict__ x1,
        const int* __restrict__ rp2, const int* __restrict__ c2, const float* __restrict__ v2,
        const uint4* __restrict__ x2,
        int xs,
        const uint4* __restrict__ xp, int ps,
        uint4* __restrict__ y1, uint4* __restrict__ y2, int ys,
        float alpha, float beta) {
    int bid = blockIdx.x;
    int half = bid >> 13;
    int n = bid & 8191;
    const int* rowptr = half ? rp2 : rp1;
    const int* cols   = half ? c2 : c1;
    const float* vals = half ? v2 : v1;
    const uint4* x    = half ? x2 : x1;
    uint4* y          = half ? y2 : y1;

    int t = threadIdx.x;
    int s = rowptr[n], e = rowptr[n + 1];
    float a0[8] = {0, 0, 0, 0, 0, 0, 0, 0};
    float a1[8] = {0, 0, 0, 0, 0, 0, 0, 0};
    bool tail = t < 16;         // 144 chunks: t and (t<16 ? 128+t)
    int t2 = 128 + t;
    for (int i = s; i < e; i += 8) {
        int   c[8];
        float v[8];
#pragma unroll
        for (int k = 0; k < 8; ++k) {
            int ii = i + k;
            bool ok = ii < e;
            int idx = ok ? ii : s;      // clamp: row non-empty here (i<e)
            c[k] = cols[idx];
            v[k] = ok ? vals[idx] : 0.f;
        }
        uint4 d[8];
#pragma unroll
        for (int k = 0; k < 8; ++k) d[k] = x[(size_t)c[k] * xs + t];
        uint4 d2[8];
        if (tail) {
#pragma unroll
            for (int k = 0; k < 8; ++k) d2[k] = x[(size_t)c[k] * xs + t2];
        }
#pragma unroll
        for (int k = 0; k < 8; ++k) fma8(a0, d[k], v[k]);
        if (tail) {
#pragma unroll
            for (int k = 0; k < 8; ++k) fma8(a1, d2[k], v[k]);
        }
    }
    uint4* yb = y + (size_t)n * ys;
    const uint4* xpb = xp + (size_t)n * ps;
    uint4 p0 = (beta != 0.f) ? xpb[t] : make_uint4(0, 0, 0, 0);
    yb[t] = blend_pack8(a0, p0, alpha, beta);
    if (tail) {
        uint4 p1 = (beta != 0.f) ? xpb[t2] : make_uint4(0, 0, 0, 0);
        yb[t2] = blend_pack8(a1, p1, alpha, beta);
    }
}

// ---------------- gate GEMM: direct-global MFMA fragments, no LDS, no barriers ----------------
// GN=4 (2048 blocks): r4's 1024 blocks = 4 blk/CU grid cap while VGPR 76 allows 6.

__global__ __launch_bounds__(256, 2) void gate_mfma(const ushort* __restrict__ Xb,
                                                    const ushort* __restrict__ WgT,
                                                    const float* __restrict__ bg,
                                                    const float* __restrict__ state,
                                                    float* __restrict__ U,
                                                    ushort* __restrict__ Xc) {
    int tid = threadIdx.x;
    int wave = tid >> 6, lane = tid & 63;
    int row = lane & 15, quad = lane >> 4;
    int c0 = wave * 32 + row;
    int c1 = c0 + 16;

    bf16x8 w0[12], w1[12];
#pragma unroll
    for (int kt = 0; kt < 12; ++kt) {
        w0[kt] = *(const bf16x8*)(WgT + (size_t)c0 * KP2 + kt * 32 + quad * 8);
        w1[kt] = *(const bf16x8*)(WgT + (size_t)c1 * KP2 + kt * 32 + quad * 8);
    }
    float bias0 = bg[c0], bias1 = bg[c1];

    // per-lane A-fragment offsets (ushort units): k' = 8*(4*kt+quad) = m*72+f0
    int offA[11];
#pragma unroll
    for (int kt = 0; kt < 11; ++kt) {
        int j = 4 * kt + quad;
        int m = j / 9;
        int f0 = 8 * (j - 9 * m);
        offA[kt] = m * SLABU + row * FP2 + f0;
    }
    int off11 = 4 * SLABU + row * FP2 + 64;  // kt=11, quad 0 only (k' 352..359)

    int nodeBase = blockIdx.x * GN;
    for (int g = 0; g < GN; ++g) {
        int n = nodeBase + g;
        const ushort* An = Xb + (size_t)n * NSTR;
        f32x4 acc0 = {0.f, 0.f, 0.f, 0.f};
        f32x4 acc1 = {0.f, 0.f, 0.f, 0.f};
#pragma unroll
        for (int kt = 0; kt < 11; ++kt) {
            bf16x8 av = *(const bf16x8*)(An + offA[kt]);
            acc0 = __builtin_amdgcn_mfma_f32_16x16x32_bf16(av, w0[kt], acc0, 0, 0, 0);
            acc1 = __builtin_amdgcn_mfma_f32_16x16x32_bf16(av, w1[kt], acc1, 0, 0, 0);
        }
        {
            bf16x8 av = {0, 0, 0, 0, 0, 0, 0, 0};
            if (quad == 0) av = *(const bf16x8*)(An + off11);
            acc0 = __builtin_amdgcn_mfma_f32_16x16x32_bf16(av, w0[11], acc0, 0, 0, 0);
            acc1 = __builtin_amdgcn_mfma_f32_16x16x32_bf16(av, w1[11], acc1, 0, 0, 0);
        }
        // D: col = lane&15 (-> c0/c1), row b = quad*4 + reg
#pragma unroll
        for (int r = 0; r < 4; ++r) {
            int b = quad * 4 + r;
            float v0 = 1.f / (1.f + __expf(-(acc0[r] + bias0)));
            float v1 = 1.f / (1.f + __expf(-(acc1[r] + bias1)));
            if (wave < 2) {  // cols 0..63: r-gate -> xc state part (bf16, separate buffer)
                float s0 = state[(size_t)b * SN + n * HID + c0];
                float s1 = state[(size_t)b * SN + n * HID + c1];
                Xc[(size_t)n * SLABU + b * FP2 + 2 + c0] = f2bf(v0 * s0);
                Xc[(size_t)n * SLABU + b * FP2 + 2 + c1] = f2bf(v1 * s1);
            } else {         // cols 64..127: u-gate (fp32)
                U[(size_t)b * SN + n * HID + (c0 - HID)] = v0;
                U[(size_t)b * SN + n * HID + (c1 - HID)] = v1;
            }
        }
    }
}

// ---------------- candidate GEMM + tanh + GRU update + output ----------------
// NOTE: U aliases out+OUTHALF (scratch in d_out) -> NO __restrict__ on U/out here.

__global__ __launch_bounds__(256, 3) void cand_mfma(const ushort* __restrict__ Xb,
                                                    const ushort* __restrict__ Xc,
                                                    const ushort* __restrict__ WcT,
                                                    const float* __restrict__ bc,
                                                    const float* __restrict__ state,
                                                    const float* U,
                                                    float* out) {
    int tid = threadIdx.x;
    int wave = tid >> 6, lane = tid & 63;
    int row = lane & 15, quad = lane >> 4;
    int c = wave * 16 + row;

    bf16x8 w[12];
#pragma unroll
    for (int kt = 0; kt < 12; ++kt)
        w[kt] = *(const bf16x8*)(WcT + (size_t)c * KP2 + kt * 32 + quad * 8);
    float bias = bc[c];

    int offA[11];
#pragma unroll
    for (int kt = 0; kt < 11; ++kt) {
        int j = 4 * kt + quad;
        int m = j / 9;
        int f0 = 8 * (j - 9 * m);
        offA[kt] = m * SLABU + row * FP2 + f0;  // m==0 offsets are also Xc-relative
    }
    int off11 = 4 * SLABU + row * FP2 + 64;

    int nodeBase = blockIdx.x * GN;
    for (int g = 0; g < GN; ++g) {
        int n = nodeBase + g;
        const ushort* AnB = Xb + (size_t)n * NSTR;
        const ushort* AnC = Xc + (size_t)n * SLABU;
        f32x4 acc = {0.f, 0.f, 0.f, 0.f};
#pragma unroll
        for (int kt = 0; kt < 11; ++kt) {
            // kt 0,1: pure slab0 (Xc). kt 2: quad0 -> Xc, quads 1..3 -> Xb slab1. kt>=3: Xb.
            const ushort* bp = (kt < 2) ? AnC
                             : (kt == 2 ? (quad == 0 ? AnC : AnB) : AnB);
            bf16x8 av = *(const bf16x8*)(bp + offA[kt]);
            acc = __builtin_amdgcn_mfma_f32_16x16x32_bf16(av, w[kt], acc, 0, 0, 0);
        }
        {
            bf16x8 av = {0, 0, 0, 0, 0, 0, 0, 0};
            if (quad == 0) av = *(const bf16x8*)(AnB + off11);
            acc = __builtin_amdgcn_mfma_f32_16x16x32_bf16(av, w[11], acc, 0, 0, 0);
        }
#pragma unroll
        for (int r = 0; r < 4; ++r) {
            int b = quad * 4 + r;
            float pre = acc[r] + bias;
            float cv = 1.f - 2.f / (__expf(2.f * pre) + 1.f);  // tanh
            size_t idx = (size_t)b * SN + n * HID + c;
            float uv = U[idx];       // read BEFORE the aliased write below
            float s = state[idx];
            float ns = uv * s + (1.f - uv) * cv;
            out[idx] = ns;
            out[OUTHALF + idx] = ns; // overwrites U[idx] (same thread, after read)
        }
    }
}

// ---------------- launch ----------------

extern "C" void kernel_launch(void* const* d_in, const int* in_sizes, int n_in,
                              void* d_out, int out_size, void* d_ws, size_t ws_size,
                              hipStream_t stream) {
    const float* inputs = (const float*)d_in[0];
    const float* state  = (const float*)d_in[1];
    const int*   esrc   = (const int*)d_in[2];
    const int*   edst   = (const int*)d_in[3];
    const float* v1     = (const float*)d_in[4];
    const float* v2     = (const float*)d_in[5];
    const float* Wg     = (const float*)d_in[6];
    const float* bg     = (const float*)d_in[7];
    const float* Wc     = (const float*)d_in[8];
    const float* bc     = (const float*)d_in[9];
    float* out = (float*)d_out;

    char* ws = (char*)d_ws;
    size_t off = 0;
    auto alloc = [&](size_t bytes) -> void* {
        void* p = ws + off;
        off += (bytes + 255) & ~(size_t)255;
        return p;
    };
    ushort* Xb     = (ushort*)alloc((size_t)NNODES * NSTR * 2);   // 94.4 MB [n][m][b][72]
    ushort* Xc     = (ushort*)alloc((size_t)NNODES * SLABU * 2);  // 18.9 MB xc slab0
    ushort* WgT    = (ushort*)alloc((size_t)128 * KP2 * 2);
    ushort* WcT    = (ushort*)alloc((size_t)64 * KP2 * 2);
    int*   counts1 = (int*)alloc(NNODES * 4);
    int*   counts2 = (int*)alloc(NNODES * 4);
    int*   rowptr1 = (int*)alloc((NNODES + 1) * 4);
    int*   rowptr2 = (int*)alloc((NNODES + 1) * 4);
    int*   cursor1 = (int*)alloc(NNODES * 4);
    int*   cursor2 = (int*)alloc(NNODES * 4);
    int*   cols1   = (int*)alloc(NEDGE * 4);
    int*   cols2   = (int*)alloc(NEDGE * 4);
    float* valsC1  = (float*)alloc(NEDGE * 4);
    float* valsC2  = (float*)alloc(NEDGE * 4);

    // U scratch lives in the second output copy (dead until cand epilogue)
    float* U = out + OUTHALF;

    uint4* Xb4 = (uint4*)Xb;
    uint4* Xc4 = (uint4*)Xc;
    auto slab = [&](int m) { return Xb4 + (size_t)m * 144; };  // slab m base, node stride 720

    // CSR build (graph shared by both diff_convs)
    zero_counts_kernel<<<(NNODES + 255) / 256, 256, 0, stream>>>(counts1, counts2);
    hist_kernel<<<(NEDGE + 255) / 256, 256, 0, stream>>>(esrc, edst, counts1, counts2);
    scan_kernel<<<2, 1024, 0, stream>>>(counts1, counts2, rowptr1, rowptr2, cursor1, cursor2);
    scatter_kernel<<<(NEDGE + 255) / 256, 256, 0, stream>>>(esrc, edst, v1, v2,
                                                            cursor1, cursor2,
                                                            cols1, valsC1, cols2, valsC2);

    // fused weight-convert + x0-build (independent work, one dispatch)
    prep_kernel<<<CWB + BXB, 256, 0, stream>>>(Wg, Wc, WgT, WcT,
                                               inputs, state, (uint*)Xb, (uint*)Xc);

    // diff_conv #1 diffusion: both graphs per dispatch (dual)
    spmm_dual<<<2 * NNODES, 128, 0, stream>>>(rowptr1, cols1, valsC1, slab(0),
                                              rowptr2, cols2, valsC2, slab(0), NSTR4,
                                              slab(0), NSTR4, slab(1), slab(3), NSTR4,
                                              1.f, 0.f);
    spmm_dual<<<2 * NNODES, 128, 0, stream>>>(rowptr1, cols1, valsC1, slab(1),
                                              rowptr2, cols2, valsC2, slab(3), NSTR4,
                                              slab(0), NSTR4, slab(2), slab(4), NSTR4,
                                              2.f, -1.f);

    // gate GEMM + sigmoid; writes U (in d_out scratch) and xc slab0 (r*state) into Xc
    gate_mfma<<<NNODES / GN, 256, 0, stream>>>(Xb, WgT, bg, state, U, Xc);

    // diff_conv #2 diffusion on xc (x0 := Xc, node stride 144 uint4)
    spmm_dual<<<2 * NNODES, 128, 0, stream>>>(rowptr1, cols1, valsC1, Xc4,
                                              rowptr2, cols2, valsC2, Xc4, XCS4,
                                              Xc4, XCS4, slab(1), slab(3), NSTR4,
                                              1.f, 0.f);
    spmm_dual<<<2 * NNODES, 128, 0, stream>>>(rowptr1, cols1, valsC1, slab(1),
                                              rowptr2, cols2, valsC2, slab(3), NSTR4,
                                              Xc4, XCS4, slab(2), slab(4), NSTR4,
                                              2.f, -1.f);

    // candidate GEMM + tanh + GRU update + duplicated output
    cand_mfma<<<NNODES / GN, 256, 0, stream>>>(Xb, Xc, WcT, bc, state, U, out);
}

// Round 14
// 557.186 us; speedup vs baseline: 1.0342x; 1.0342x over previous
//
#include <hip/hip_runtime.h>
#include <cstddef>
#include <cstdint>

#define NNODES 8192
#define BATCH  16
#define HID    64
#define NEDGE  131072
#define SN     524288   // NNODES * HID (per-batch state stride)
#define OUTHALF 8388608 // BATCH * SN
#define FP2    72       // padded per-slab feature dim (66 real + 6 zero); 72 = 9*8
#define SLABU  1152     // ushorts per (node, slab) = 16*72
#define NSTR   5760     // ushorts per node = 5*SLABU
#define NSTR4  720      // uint4 per node in Xb (5760 ushorts / 8 per uint4)
#define XCS4   144      // uint4 per node in Xc (slab0-only buffer, 1152/8)
#define KP2    384      // padded K' = 12 k-tiles of 32 (360 real + 24 zero)
#define GN     8        // nodes per GEMM block (GN perf-neutral r12/r13; 8 = deeper pipeline)
#define CWB    288      // convert_w blocks inside prep_kernel (192*KP2/256)
#define BXB    18432    // build_x0 blocks inside prep_kernel (NNODES*BATCH*36/256)

typedef __attribute__((ext_vector_type(8))) short bf16x8;
typedef __attribute__((ext_vector_type(4))) float f32x4;

static __device__ __forceinline__ float bf2f(ushort u) {
    union { uint32_t i; float f; } c; c.i = ((uint32_t)u) << 16; return c.f;
}
static __device__ __forceinline__ ushort f2bf(float f) {
    union { float f; uint32_t i; } c; c.f = f;
    uint32_t lsb = (c.i >> 16) & 1;
    return (ushort)((c.i + 0x7fffu + lsb) >> 16);
}

// ---------------- CSR construction ----------------

__global__ void zero_counts_kernel(int* __restrict__ c1, int* __restrict__ c2) {
    int i = blockIdx.x * 256 + threadIdx.x;
    if (i < NNODES) { c1[i] = 0; c2[i] = 0; }
}

__global__ void hist_kernel(const int* __restrict__ src, const int* __restrict__ dst,
                            int* __restrict__ c1, int* __restrict__ c2) {
    int e = blockIdx.x * 256 + threadIdx.x;
    if (e < NEDGE) {
        atomicAdd(&c1[src[e]], 1);
        atomicAdd(&c2[dst[e]], 1);
    }
}

// Both CSR scans in ONE dispatch: block 0 -> graph 1, block 1 -> graph 2.
__global__ __launch_bounds__(1024) void scan_kernel(const int* __restrict__ counts1,
                                                    const int* __restrict__ counts2,
                                                    int* __restrict__ rowptr1,
                                                    int* __restrict__ rowptr2,
                                                    int* __restrict__ cursor1,
                                                    int* __restrict__ cursor2) {
    const int* counts = blockIdx.x ? counts2 : counts1;
    int* rowptr       = blockIdx.x ? rowptr2 : rowptr1;
    int* cursor       = blockIdx.x ? cursor2 : cursor1;
    __shared__ int sh[1024];
    int tid = threadIdx.x;
    int base = tid * 8;
    int local[8];
    int sum = 0;
#pragma unroll
    for (int j = 0; j < 8; ++j) { local[j] = counts[base + j]; sum += local[j]; }
    sh[tid] = sum;
    __syncthreads();
    for (int off = 1; off < 1024; off <<= 1) {
        int v = (tid >= off) ? sh[tid - off] : 0;
        __syncthreads();
        sh[tid] += v;
        __syncthreads();
    }
    int p = sh[tid] - sum;
#pragma unroll
    for (int j = 0; j < 8; ++j) {
        cursor[base + j] = p;
        p += local[j];
        rowptr[base + j + 1] = p;
    }
    if (tid == 0) rowptr[0] = 0;
}

__global__ void scatter_kernel(const int* __restrict__ src, const int* __restrict__ dst,
                               const float* __restrict__ v1, const float* __restrict__ v2,
                               int* __restrict__ cur1, int* __restrict__ cur2,
                               int* __restrict__ cols1, float* __restrict__ valsC1,
                               int* __restrict__ cols2, float* __restrict__ valsC2) {
    int e = blockIdx.x * 256 + threadIdx.x;
    if (e < NEDGE) {
        int r1 = src[e];
        int p1 = atomicAdd(&cur1[r1], 1);
        cols1[p1] = dst[e];
        valsC1[p1] = v1[e];
        int r2 = dst[e];
        int p2 = atomicAdd(&cur2[r2], 1);
        cols2[p2] = src[e];
        valsC2[p2] = v2[e];
    }
}

// -------- fused prep: convert_w (blocks [0,CWB)) + build_x0 (blocks [CWB,CWB+BXB)) --------

__global__ void prep_kernel(const float* __restrict__ Wg, const float* __restrict__ Wc,
                            ushort* __restrict__ WgT, ushort* __restrict__ WcT,
                            const float* __restrict__ inputs, const float* __restrict__ state,
                            uint* __restrict__ Xb_u, uint* __restrict__ Xc_u) {
    if (blockIdx.x < CWB) {
        int i = blockIdx.x * 256 + threadIdx.x;
        if (i >= 192 * KP2) return;
        int col = i / KP2, k2 = i - col * KP2;
        int m = k2 / FP2, f = k2 - m * FP2;
        bool valid = (m < 5) && (f < 66);
        int ko = f * 5 + m;
        if (col < 128) {
            WgT[col * KP2 + k2] = valid ? f2bf(Wg[ko * 128 + col]) : (ushort)0;
        } else {
            int c = col - 128;
            WcT[c * KP2 + k2] = valid ? f2bf(Wc[ko * 64 + c]) : (ushort)0;
        }
        return;
    }
    int t = (blockIdx.x - CWB) * 256 + threadIdx.x;
    if (t >= NNODES * BATCH * 36) return;
    int n = t / 576;           // 576 = 16*36 uints per node-slab
    int r = t - n * 576;       // b*36 + j
    int b = r / 36;
    int j = r - b * 36;
    int f0 = 2 * j;
    uint val = 0;
    if (f0 == 0) {
        float v0 = inputs[(size_t)b * (NNODES * 2) + n * 2 + 0];
        float v1 = inputs[(size_t)b * (NNODES * 2) + n * 2 + 1];
        val = (uint)f2bf(v0) | ((uint)f2bf(v1) << 16);
    } else if (f0 < 66) {
        float v0 = state[(size_t)b * SN + n * HID + (f0 - 2)];
        float v1 = state[(size_t)b * SN + n * HID + (f0 - 1)];
        val = (uint)f2bf(v0) | ((uint)f2bf(v1) << 16);
    }
    Xb_u[(size_t)n * 2880 + r] = val;               // slab0 = first 576 uints of node
    if (f0 == 0 || f0 >= 66) Xc_u[t] = val;         // inputs + zero pads of xc slab0
}

// ---------------- SPMM (bf16 rows, fp32 accumulate), 8-wide PREDICATED, dual-graph ----------------
// FROZEN CONTROL (r12 engine): logical gather 7.2 TB/s; three structures converge here.

static __device__ __forceinline__ void fma8(float* acc, uint4 d, float v) {
    acc[0] += v * bf2f((ushort)(d.x));  acc[1] += v * bf2f((ushort)(d.x >> 16));
    acc[2] += v * bf2f((ushort)(d.y));  acc[3] += v * bf2f((ushort)(d.y >> 16));
    acc[4] += v * bf2f((ushort)(d.z));  acc[5] += v * bf2f((ushort)(d.z >> 16));
    acc[6] += v * bf2f((ushort)(d.w));  acc[7] += v * bf2f((ushort)(d.w >> 16));
}

static __device__ __forceinline__ uint4 blend_pack8(const float* acc, uint4 p,
                                                    float alpha, float beta) {
    float o[8];
    o[0] = alpha * acc[0] + beta * bf2f((ushort)(p.x));
    o[1] = alpha * acc[1] + beta * bf2f((ushort)(p.x >> 16));
    o[2] = alpha * acc[2] + beta * bf2f((ushort)(p.y));
    o[3] = alpha * acc[3] + beta * bf2f((ushort)(p.y >> 16));
    o[4] = alpha * acc[4] + beta * bf2f((ushort)(p.z));
    o[5] = alpha * acc[5] + beta * bf2f((ushort)(p.z >> 16));
    o[6] = alpha * acc[6] + beta * bf2f((ushort)(p.w));
    o[7] = alpha * acc[7] + beta * bf2f((ushort)(p.w >> 16));
    uint4 r;
    r.x = (uint32_t)f2bf(o[0]) | ((uint32_t)f2bf(o[1]) << 16);
    r.y = (uint32_t)f2bf(o[2]) | ((uint32_t)f2bf(o[3]) << 16);
    r.z = (uint32_t)f2bf(o[4]) | ((uint32_t)f2bf(o[5]) << 16);
    r.w = (uint32_t)f2bf(o[6]) | ((uint32_t)f2bf(o[7]) << 16);
    return r;
}

__global__ __launch_bounds__(128) void spmm_dual(
        const int* __restrict__ rp1, const int* __restrict__ c1, const float* __restrict__ v1,
        const uint4* __restrict__ x1,
        const int* __restrict__ rp2, const int* __restrict__ c2, const float* __restrict__ v2,
        const uint4* __restrict__ x2,
        int xs,
        const uint4* __restrict__ xp, int ps,
        uint4* __restrict__ y1, uint4* __restrict__ y2, int ys,
        float alpha, float beta) {
    int bid = blockIdx.x;
    int half = bid >> 13;
    int n = bid & 8191;
    const int* rowptr = half ? rp2 : rp1;
    const int* cols   = half ? c2 : c1;
    const float* vals = half ? v2 : v1;
    const uint4* x    = half ? x2 : x1;
    uint4* y          = half ? y2 : y1;

    int t = threadIdx.x;
    int s = rowptr[n], e = rowptr[n + 1];
    float a0[8] = {0, 0, 0, 0, 0, 0, 0, 0};
    float a1[8] = {0, 0, 0, 0, 0, 0, 0, 0};
    bool tail = t < 16;         // 144 chunks: t and (t<16 ? 128+t)
    int t2 = 128 + t;
    for (int i = s; i < e; i += 8) {
        int   c[8];
        float v[8];
#pragma unroll
        for (int k = 0; k < 8; ++k) {
            int ii = i + k;
            bool ok = ii < e;
            int idx = ok ? ii : s;      // clamp: row non-empty here (i<e)
            c[k] = cols[idx];
            v[k] = ok ? vals[idx] : 0.f;
        }
        uint4 d[8];
#pragma unroll
        for (int k = 0; k < 8; ++k) d[k] = x[(size_t)c[k] * xs + t];
        uint4 d2[8];
        if (tail) {
#pragma unroll
            for (int k = 0; k < 8; ++k) d2[k] = x[(size_t)c[k] * xs + t2];
        }
#pragma unroll
        for (int k = 0; k < 8; ++k) fma8(a0, d[k], v[k]);
        if (tail) {
#pragma unroll
            for (int k = 0; k < 8; ++k) fma8(a1, d2[k], v[k]);
        }
    }
    uint4* yb = y + (size_t)n * ys;
    const uint4* xpb = xp + (size_t)n * ps;
    uint4 p0 = (beta != 0.f) ? xpb[t] : make_uint4(0, 0, 0, 0);
    yb[t] = blend_pack8(a0, p0, alpha, beta);
    if (tail) {
        uint4 p1 = (beta != 0.f) ? xpb[t2] : make_uint4(0, 0, 0, 0);
        yb[t2] = blend_pack8(a1, p1, alpha, beta);
    }
}

// ---------------- gate GEMM: direct-global MFMA fragments + node-loop software pipeline ----------------
// A-fragments for node g+1 are prefetched (double-buffered regs) during node g's
// MFMAs: hides the 12-dependent-load latency chain that VGPR=76 showed the
// compiler was NOT hiding (24 hoisted w-frags alone need 96 VGPRs).

__global__ __launch_bounds__(256, 2) void gate_mfma(const ushort* __restrict__ Xb,
                                                    const ushort* __restrict__ WgT,
                                                    const float* __restrict__ bg,
                                                    const float* __restrict__ state,
                                                    float* __restrict__ U,
                                                    ushort* __restrict__ Xc) {
    int tid = threadIdx.x;
    int wave = tid >> 6, lane = tid & 63;
    int row = lane & 15, quad = lane >> 4;
    int c0 = wave * 32 + row;
    int c1 = c0 + 16;

    bf16x8 w0[12], w1[12];
#pragma unroll
    for (int kt = 0; kt < 12; ++kt) {
        w0[kt] = *(const bf16x8*)(WgT + (size_t)c0 * KP2 + kt * 32 + quad * 8);
        w1[kt] = *(const bf16x8*)(WgT + (size_t)c1 * KP2 + kt * 32 + quad * 8);
    }
    float bias0 = bg[c0], bias1 = bg[c1];

    // per-lane A-fragment offsets (ushort units): k' = 8*(4*kt+quad) = m*72+f0
    int offA[11];
#pragma unroll
    for (int kt = 0; kt < 11; ++kt) {
        int j = 4 * kt + quad;
        int m = j / 9;
        int f0 = 8 * (j - 9 * m);
        offA[kt] = m * SLABU + row * FP2 + f0;
    }
    int off11 = 4 * SLABU + row * FP2 + 64;  // kt=11, quad 0 only (k' 352..359)
    const bf16x8 zf = {0, 0, 0, 0, 0, 0, 0, 0};

    int nodeBase = blockIdx.x * GN;
    bf16x8 aC[12], aN[12];
    {   // prologue: node nodeBase
        const ushort* An = Xb + (size_t)nodeBase * NSTR;
#pragma unroll
        for (int kt = 0; kt < 11; ++kt) aC[kt] = *(const bf16x8*)(An + offA[kt]);
        aC[11] = (quad == 0) ? *(const bf16x8*)(An + off11) : zf;
    }
    for (int g = 0; g < GN; ++g) {
        int n = nodeBase + g;
        if (g + 1 < GN) {   // prefetch node n+1 (independent of current MFMAs)
            const ushort* An2 = Xb + (size_t)(n + 1) * NSTR;
#pragma unroll
            for (int kt = 0; kt < 11; ++kt) aN[kt] = *(const bf16x8*)(An2 + offA[kt]);
            aN[11] = (quad == 0) ? *(const bf16x8*)(An2 + off11) : zf;
        }
        f32x4 acc0 = {0.f, 0.f, 0.f, 0.f};
        f32x4 acc1 = {0.f, 0.f, 0.f, 0.f};
#pragma unroll
        for (int kt = 0; kt < 12; ++kt) {
            acc0 = __builtin_amdgcn_mfma_f32_16x16x32_bf16(aC[kt], w0[kt], acc0, 0, 0, 0);
            acc1 = __builtin_amdgcn_mfma_f32_16x16x32_bf16(aC[kt], w1[kt], acc1, 0, 0, 0);
        }
        // D: col = lane&15 (-> c0/c1), row b = quad*4 + reg
#pragma unroll
        for (int r = 0; r < 4; ++r) {
            int b = quad * 4 + r;
            float v0 = 1.f / (1.f + __expf(-(acc0[r] + bias0)));
            float v1 = 1.f / (1.f + __expf(-(acc1[r] + bias1)));
            if (wave < 2) {  // cols 0..63: r-gate -> xc state part (bf16, separate buffer)
                float s0 = state[(size_t)b * SN + n * HID + c0];
                float s1 = state[(size_t)b * SN + n * HID + c1];
                Xc[(size_t)n * SLABU + b * FP2 + 2 + c0] = f2bf(v0 * s0);
                Xc[(size_t)n * SLABU + b * FP2 + 2 + c1] = f2bf(v1 * s1);
            } else {         // cols 64..127: u-gate (fp32)
                U[(size_t)b * SN + n * HID + (c0 - HID)] = v0;
                U[(size_t)b * SN + n * HID + (c1 - HID)] = v1;
            }
        }
        if (g + 1 < GN) {
#pragma unroll
            for (int kt = 0; kt < 12; ++kt) aC[kt] = aN[kt];
        }
    }
}

// ---------------- candidate GEMM + tanh + GRU update + output ----------------
// Same node-loop software pipeline. U aliases out+OUTHALF -> NO __restrict__ on U/out.

__global__ __launch_bounds__(256, 2) void cand_mfma(const ushort* __restrict__ Xb,
                                                    const ushort* __restrict__ Xc,
                                                    const ushort* __restrict__ WcT,
                                                    const float* __restrict__ bc,
                                                    const float* __restrict__ state,
                                                    const float* U,
                                                    float* out) {
    int tid = threadIdx.x;
    int wave = tid >> 6, lane = tid & 63;
    int row = lane & 15, quad = lane >> 4;
    int c = wave * 16 + row;

    bf16x8 w[12];
#pragma unroll
    for (int kt = 0; kt < 12; ++kt)
        w[kt] = *(const bf16x8*)(WcT + (size_t)c * KP2 + kt * 32 + quad * 8);
    float bias = bc[c];

    int offA[11];
#pragma unroll
    for (int kt = 0; kt < 11; ++kt) {
        int j = 4 * kt + quad;
        int m = j / 9;
        int f0 = 8 * (j - 9 * m);
        offA[kt] = m * SLABU + row * FP2 + f0;  // m==0 offsets are also Xc-relative
    }
    int off11 = 4 * SLABU + row * FP2 + 64;
    const bf16x8 zf = {0, 0, 0, 0, 0, 0, 0, 0};

    int nodeBase = blockIdx.x * GN;
    bf16x8 aC[12], aN[12];
    auto loadA = [&](int n, bf16x8* a) {
        const ushort* AnB = Xb + (size_t)n * NSTR;
        const ushort* AnC = Xc + (size_t)n * SLABU;
#pragma unroll
        for (int kt = 0; kt < 11; ++kt) {
            // kt 0,1: pure slab0 (Xc). kt 2: quad0 -> Xc, quads 1..3 -> Xb slab1. kt>=3: Xb.
            const ushort* bp = (kt < 2) ? AnC
                             : (kt == 2 ? (quad == 0 ? AnC : AnB) : AnB);
            a[kt] = *(const bf16x8*)(bp + offA[kt]);
        }
        a[11] = (quad == 0) ? *(const bf16x8*)(AnB + off11) : zf;
    };
    loadA(nodeBase, aC);
    for (int g = 0; g < GN; ++g) {
        int n = nodeBase + g;
        if (g + 1 < GN) loadA(n + 1, aN);
        f32x4 acc = {0.f, 0.f, 0.f, 0.f};
#pragma unroll
        for (int kt = 0; kt < 12; ++kt)
            acc = __builtin_amdgcn_mfma_f32_16x16x32_bf16(aC[kt], w[kt], acc, 0, 0, 0);
#pragma unroll
        for (int r = 0; r < 4; ++r) {
            int b = quad * 4 + r;
            float pre = acc[r] + bias;
            float cv = 1.f - 2.f / (__expf(2.f * pre) + 1.f);  // tanh
            size_t idx = (size_t)b * SN + n * HID + c;
            float uv = U[idx];       // read BEFORE the aliased write below
            float s = state[idx];
            float ns = uv * s + (1.f - uv) * cv;
            out[idx] = ns;
            out[OUTHALF + idx] = ns; // overwrites U[idx] (same thread, after read)
        }
        if (g + 1 < GN) {
#pragma unroll
            for (int kt = 0; kt < 12; ++kt) aC[kt] = aN[kt];
        }
    }
}

// ---------------- launch ----------------

extern "C" void kernel_launch(void* const* d_in, const int* in_sizes, int n_in,
                              void* d_out, int out_size, void* d_ws, size_t ws_size,
                              hipStream_t stream) {
    const float* inputs = (const float*)d_in[0];
    const float* state  = (const float*)d_in[1];
    const int*   esrc   = (const int*)d_in[2];
    const int*   edst   = (const int*)d_in[3];
    const float* v1     = (const float*)d_in[4];
    const float* v2     = (const float*)d_in[5];
    const float* Wg     = (const float*)d_in[6];
    const float* bg     = (const float*)d_in[7];
    const float* Wc     = (const float*)d_in[8];
    const float* bc     = (const float*)d_in[9];
    float* out = (float*)d_out;

    char* ws = (char*)d_ws;
    size_t off = 0;
    auto alloc = [&](size_t bytes) -> void* {
        void* p = ws + off;
        off += (bytes + 255) & ~(size_t)255;
        return p;
    };
    ushort* Xb     = (ushort*)alloc((size_t)NNODES * NSTR * 2);   // 94.4 MB [n][m][b][72]
    ushort* Xc     = (ushort*)alloc((size_t)NNODES * SLABU * 2);  // 18.9 MB xc slab0
    ushort* WgT    = (ushort*)alloc((size_t)128 * KP2 * 2);
    ushort* WcT    = (ushort*)alloc((size_t)64 * KP2 * 2);
    int*   counts1 = (int*)alloc(NNODES * 4);
    int*   counts2 = (int*)alloc(NNODES * 4);
    int*   rowptr1 = (int*)alloc((NNODES + 1) * 4);
    int*   rowptr2 = (int*)alloc((NNODES + 1) * 4);
    int*   cursor1 = (int*)alloc(NNODES * 4);
    int*   cursor2 = (int*)alloc(NNODES * 4);
    int*   cols1   = (int*)alloc(NEDGE * 4);
    int*   cols2   = (int*)alloc(NEDGE * 4);
    float* valsC1  = (float*)alloc(NEDGE * 4);
    float* valsC2  = (float*)alloc(NEDGE * 4);

    // U scratch lives in the second output copy (dead until cand epilogue)
    float* U = out + OUTHALF;

    uint4* Xb4 = (uint4*)Xb;
    uint4* Xc4 = (uint4*)Xc;
    auto slab = [&](int m) { return Xb4 + (size_t)m * 144; };  // slab m base, node stride 720

    // CSR build (graph shared by both diff_convs)
    zero_counts_kernel<<<(NNODES + 255) / 256, 256, 0, stream>>>(counts1, counts2);
    hist_kernel<<<(NEDGE + 255) / 256, 256, 0, stream>>>(esrc, edst, counts1, counts2);
    scan_kernel<<<2, 1024, 0, stream>>>(counts1, counts2, rowptr1, rowptr2, cursor1, cursor2);
    scatter_kernel<<<(NEDGE + 255) / 256, 256, 0, stream>>>(esrc, edst, v1, v2,
                                                            cursor1, cursor2,
                                                            cols1, valsC1, cols2, valsC2);

    // fused weight-convert + x0-build (independent work, one dispatch)
    prep_kernel<<<CWB + BXB, 256, 0, stream>>>(Wg, Wc, WgT, WcT,
                                               inputs, state, (uint*)Xb, (uint*)Xc);

    // diff_conv #1 diffusion: both graphs per dispatch (dual)
    spmm_dual<<<2 * NNODES, 128, 0, stream>>>(rowptr1, cols1, valsC1, slab(0),
                                              rowptr2, cols2, valsC2, slab(0), NSTR4,
                                              slab(0), NSTR4, slab(1), slab(3), NSTR4,
                                              1.f, 0.f);
    spmm_dual<<<2 * NNODES, 128, 0, stream>>>(rowptr1, cols1, valsC1, slab(1),
                                              rowptr2, cols2, valsC2, slab(3), NSTR4,
                                              slab(0), NSTR4, slab(2), slab(4), NSTR4,
                                              2.f, -1.f);

    // gate GEMM + sigmoid; writes U (in d_out scratch) and xc slab0 (r*state) into Xc
    gate_mfma<<<NNODES / GN, 256, 0, stream>>>(Xb, WgT, bg, state, U, Xc);

    // diff_conv #2 diffusion on xc (x0 := Xc, node stride 144 uint4)
    spmm_dual<<<2 * NNODES, 128, 0, stream>>>(rowptr1, cols1, valsC1, Xc4,
                                              rowptr2, cols2, valsC2, Xc4, XCS4,
                                              Xc4, XCS4, slab(1), slab(3), NSTR4,
                                              1.f, 0.f);
    spmm_dual<<<2 * NNODES, 128, 0, stream>>>(rowptr1, cols1, valsC1, slab(1),
                                              rowptr2, cols2, valsC2, slab(3), NSTR4,
                                              Xc4, XCS4, slab(2), slab(4), NSTR4,
                                              2.f, -1.f);

    // candidate GEMM + tanh + GRU update + duplicated output
    cand_mfma<<<NNODES / GN, 256, 0, stream>>>(Xb, Xc, WcT, bc, state, U, out);
}

// Round 16
// 554.518 us; speedup vs baseline: 1.0392x; 1.0048x over previous
//
#include <hip/hip_runtime.h>
#include <cstddef>
#include <cstdint>

#define NNODES 8192
#define BATCH  16
#define HID    64
#define NEDGE  131072
#define SN     524288   // NNODES * HID (per-batch state stride)
#define OUTHALF 8388608 // BATCH * SN
#define FP2    72       // padded per-slab feature dim (66 real + 6 zero); 72 = 9*8
#define SLABU  1152     // ushorts per (node, slab) = 16*72
#define NSTR   5760     // ushorts per node = 5*SLABU
#define NSTR4  720      // uint4 per node in Xb (5760 ushorts / 8 per uint4)
#define XCS4   144      // uint4 per node in Xc (slab0-only buffer, 1152/8)
#define KP2    384      // padded K' = 12 k-tiles of 32 (360 real + 24 zero)
#define GN     8        // nodes per GEMM block
#define CWB    288      // convert_w blocks inside prep_kernel (192*KP2/256)
#define BXB    18432    // build_x0 blocks inside prep_kernel (NNODES*BATCH*36/256)

typedef __attribute__((ext_vector_type(8))) short bf16x8;
typedef __attribute__((ext_vector_type(4))) float f32x4;

static __device__ __forceinline__ float bf2f(ushort u) {
    union { uint32_t i; float f; } c; c.i = ((uint32_t)u) << 16; return c.f;
}
static __device__ __forceinline__ ushort f2bf(float f) {
    union { float f; uint32_t i; } c; c.f = f;
    uint32_t lsb = (c.i >> 16) & 1;
    return (ushort)((c.i + 0x7fffu + lsb) >> 16);
}

// ---------------- CSR construction ----------------

__global__ void hist_kernel(const int* __restrict__ src, const int* __restrict__ dst,
                            int* __restrict__ c1, int* __restrict__ c2) {
    int e = blockIdx.x * 256 + threadIdx.x;
    if (e < NEDGE) {
        atomicAdd(&c1[src[e]], 1);
        atomicAdd(&c2[dst[e]], 1);
    }
}

// Both CSR scans in ONE dispatch: block 0 -> graph 1, block 1 -> graph 2.
__global__ __launch_bounds__(1024) void scan_kernel(const int* __restrict__ counts1,
                                                    const int* __restrict__ counts2,
                                                    int* __restrict__ rowptr1,
                                                    int* __restrict__ rowptr2,
                                                    int* __restrict__ cursor1,
                                                    int* __restrict__ cursor2) {
    const int* counts = blockIdx.x ? counts2 : counts1;
    int* rowptr       = blockIdx.x ? rowptr2 : rowptr1;
    int* cursor       = blockIdx.x ? cursor2 : cursor1;
    __shared__ int sh[1024];
    int tid = threadIdx.x;
    int base = tid * 8;
    int local[8];
    int sum = 0;
#pragma unroll
    for (int j = 0; j < 8; ++j) { local[j] = counts[base + j]; sum += local[j]; }
    sh[tid] = sum;
    __syncthreads();
    for (int off = 1; off < 1024; off <<= 1) {
        int v = (tid >= off) ? sh[tid - off] : 0;
        __syncthreads();
        sh[tid] += v;
        __syncthreads();
    }
    int p = sh[tid] - sum;
#pragma unroll
    for (int j = 0; j < 8; ++j) {
        cursor[base + j] = p;
        p += local[j];
        rowptr[base + j + 1] = p;
    }
    if (tid == 0) rowptr[0] = 0;
}

__global__ void scatter_kernel(const int* __restrict__ src, const int* __restrict__ dst,
                               const float* __restrict__ v1, const float* __restrict__ v2,
                               int* __restrict__ cur1, int* __restrict__ cur2,
                               int* __restrict__ cols1, float* __restrict__ valsC1,
                               int* __restrict__ cols2, float* __restrict__ valsC2) {
    int e = blockIdx.x * 256 + threadIdx.x;
    if (e < NEDGE) {
        int r1 = src[e];
        int p1 = atomicAdd(&cur1[r1], 1);
        cols1[p1] = dst[e];
        valsC1[p1] = v1[e];
        int r2 = dst[e];
        int p2 = atomicAdd(&cur2[r2], 1);
        cols2[p2] = src[e];
        valsC2[p2] = v2[e];
    }
}

// -------- fused prep: convert_w (blocks [0,CWB)) + build_x0 (blocks [CWB,CWB+BXB)) --------

__global__ void prep_kernel(const float* __restrict__ Wg, const float* __restrict__ Wc,
                            ushort* __restrict__ WgT, ushort* __restrict__ WcT,
                            const float* __restrict__ inputs, const float* __restrict__ state,
                            uint* __restrict__ Xb_u, uint* __restrict__ Xc_u) {
    if (blockIdx.x < CWB) {
        int i = blockIdx.x * 256 + threadIdx.x;
        if (i >= 192 * KP2) return;
        int col = i / KP2, k2 = i - col * KP2;
        int m = k2 / FP2, f = k2 - m * FP2;
        bool valid = (m < 5) && (f < 66);
        int ko = f * 5 + m;
        if (col < 128) {
            WgT[col * KP2 + k2] = valid ? f2bf(Wg[ko * 128 + col]) : (ushort)0;
        } else {
            int c = col - 128;
            WcT[c * KP2 + k2] = valid ? f2bf(Wc[ko * 64 + c]) : (ushort)0;
        }
        return;
    }
    int t = (blockIdx.x - CWB) * 256 + threadIdx.x;
    if (t >= NNODES * BATCH * 36) return;
    int n = t / 576;           // 576 = 16*36 uints per node-slab
    int r = t - n * 576;       // b*36 + j
    int b = r / 36;
    int j = r - b * 36;
    int f0 = 2 * j;
    uint val = 0;
    if (f0 == 0) {
        float v0 = inputs[(size_t)b * (NNODES * 2) + n * 2 + 0];
        float v1 = inputs[(size_t)b * (NNODES * 2) + n * 2 + 1];
        val = (uint)f2bf(v0) | ((uint)f2bf(v1) << 16);
    } else if (f0 < 66) {
        float v0 = state[(size_t)b * SN + n * HID + (f0 - 2)];
        float v1 = state[(size_t)b * SN + n * HID + (f0 - 1)];
        val = (uint)f2bf(v0) | ((uint)f2bf(v1) << 16);
    }
    Xb_u[(size_t)n * 2880 + r] = val;               // slab0 = first 576 uints of node
    if (f0 == 0 || f0 >= 66) Xc_u[t] = val;         // inputs + zero pads of xc slab0
}

// ---------------- SPMM (bf16 rows, fp32 accumulate), 8-wide PREDICATED, dual-graph ----------------
// FROZEN CONTROL (r12 engine): logical gather 7.2 TB/s; three structures converge here.

static __device__ __forceinline__ void fma8(float* acc, uint4 d, float v) {
    acc[0] += v * bf2f((ushort)(d.x));  acc[1] += v * bf2f((ushort)(d.x >> 16));
    acc[2] += v * bf2f((ushort)(d.y));  acc[3] += v * bf2f((ushort)(d.y >> 16));
    acc[4] += v * bf2f((ushort)(d.z));  acc[5] += v * bf2f((ushort)(d.z >> 16));
    acc[6] += v * bf2f((ushort)(d.w));  acc[7] += v * bf2f((ushort)(d.w >> 16));
}

static __device__ __forceinline__ uint4 blend_pack8(const float* acc, uint4 p,
                                                    float alpha, float beta) {
    float o[8];
    o[0] = alpha * acc[0] + beta * bf2f((ushort)(p.x));
    o[1] = alpha * acc[1] + beta * bf2f((ushort)(p.x >> 16));
    o[2] = alpha * acc[2] + beta * bf2f((ushort)(p.y));
    o[3] = alpha * acc[3] + beta * bf2f((ushort)(p.y >> 16));
    o[4] = alpha * acc[4] + beta * bf2f((ushort)(p.z));
    o[5] = alpha * acc[5] + beta * bf2f((ushort)(p.z >> 16));
    o[6] = alpha * acc[6] + beta * bf2f((ushort)(p.w));
    o[7] = alpha * acc[7] + beta * bf2f((ushort)(p.w >> 16));
    uint4 r;
    r.x = (uint32_t)f2bf(o[0]) | ((uint32_t)f2bf(o[1]) << 16);
    r.y = (uint32_t)f2bf(o[2]) | ((uint32_t)f2bf(o[3]) << 16);
    r.z = (uint32_t)f2bf(o[4]) | ((uint32_t)f2bf(o[5]) << 16);
    r.w = (uint32_t)f2bf(o[6]) | ((uint32_t)f2bf(o[7]) << 16);
    return r;
}

__global__ __launch_bounds__(128) void spmm_dual(
        const int* __restrict__ rp1, const int* __restrict__ c1, const float* __restrict__ v1,
        const uint4* __restrict__ x1,
        const int* __restrict__ rp2, const int* __restrict__ c2, const float* __restrict__ v2,
        const uint4* __restrict__ x2,
        int xs,
        const uint4* __restrict__ xp, int ps,
        uint4* __restrict__ y1, uint4* __restrict__ y2, int ys,
        float alpha, float beta) {
    int bid = blockIdx.x;
    int half = bid >> 13;
    int n = bid & 8191;
    const int* rowptr = half ? rp2 : rp1;
    const int* cols   = half ? c2 : c1;
    const float* vals = half ? v2 : v1;
    const uint4* x    = half ? x2 : x1;
    uint4* y          = half ? y2 : y1;

    int t = threadIdx.x;
    int s = rowptr[n], e = rowptr[n + 1];
    float a0[8] = {0, 0, 0, 0, 0, 0, 0, 0};
    float a1[8] = {0, 0, 0, 0, 0, 0, 0, 0};
    bool tail = t < 16;         // 144 chunks: t and (t<16 ? 128+t)
    int t2 = 128 + t;
    for (int i = s; i < e; i += 8) {
        int   c[8];
        float v[8];
#pragma unroll
        for (int k = 0; k < 8; ++k) {
            int ii = i + k;
            bool ok = ii < e;
            int idx = ok ? ii : s;      // clamp: row non-empty here (i<e)
            c[k] = cols[idx];
            v[k] = ok ? vals[idx] : 0.f;
        }
        uint4 d[8];
#pragma unroll
        for (int k = 0; k < 8; ++k) d[k] = x[(size_t)c[k] * xs + t];
        uint4 d2[8];
        if (tail) {
#pragma unroll
            for (int k = 0; k < 8; ++k) d2[k] = x[(size_t)c[k] * xs + t2];
        }
#pragma unroll
        for (int k = 0; k < 8; ++k) fma8(a0, d[k], v[k]);
        if (tail) {
#pragma unroll
            for (int k = 0; k < 8; ++k) fma8(a1, d2[k], v[k]);
        }
    }
    uint4* yb = y + (size_t)n * ys;
    const uint4* xpb = xp + (size_t)n * ps;
    uint4 p0 = (beta != 0.f) ? xpb[t] : make_uint4(0, 0, 0, 0);
    yb[t] = blend_pack8(a0, p0, alpha, beta);
    if (tail) {
        uint4 p1 = (beta != 0.f) ? xpb[t2] : make_uint4(0, 0, 0, 0);
        yb[t2] = blend_pack8(a1, p1, alpha, beta);
    }
}

// ---------------- gate GEMM: direct-global MFMA fragments + node-loop software pipeline ----------------
// r*state reads state from Xb slab0 (bf16, node-contiguous, L1/L2-hot from the
// A-fragment stream) instead of the cold 2MB-strided fp32 state buffer.

__global__ __launch_bounds__(256, 2) void gate_mfma(const ushort* __restrict__ Xb,
                                                    const ushort* __restrict__ WgT,
                                                    const float* __restrict__ bg,
                                                    float* __restrict__ U,
                                                    ushort* __restrict__ Xc) {
    int tid = threadIdx.x;
    int wave = tid >> 6, lane = tid & 63;
    int row = lane & 15, quad = lane >> 4;
    int c0 = wave * 32 + row;
    int c1 = c0 + 16;

    bf16x8 w0[12], w1[12];
#pragma unroll
    for (int kt = 0; kt < 12; ++kt) {
        w0[kt] = *(const bf16x8*)(WgT + (size_t)c0 * KP2 + kt * 32 + quad * 8);
        w1[kt] = *(const bf16x8*)(WgT + (size_t)c1 * KP2 + kt * 32 + quad * 8);
    }
    float bias0 = bg[c0], bias1 = bg[c1];

    // per-lane A-fragment offsets (ushort units): k' = 8*(4*kt+quad) = m*72+f0
    int offA[11];
#pragma unroll
    for (int kt = 0; kt < 11; ++kt) {
        int j = 4 * kt + quad;
        int m = j / 9;
        int f0 = 8 * (j - 9 * m);
        offA[kt] = m * SLABU + row * FP2 + f0;
    }
    int off11 = 4 * SLABU + row * FP2 + 64;  // kt=11, quad 0 only (k' 352..359)
    const bf16x8 zf = {0, 0, 0, 0, 0, 0, 0, 0};

    int nodeBase = blockIdx.x * GN;
    bf16x8 aC[12], aN[12];
    {   // prologue: node nodeBase
        const ushort* An = Xb + (size_t)nodeBase * NSTR;
#pragma unroll
        for (int kt = 0; kt < 11; ++kt) aC[kt] = *(const bf16x8*)(An + offA[kt]);
        aC[11] = (quad == 0) ? *(const bf16x8*)(An + off11) : zf;
    }
    for (int g = 0; g < GN; ++g) {
        int n = nodeBase + g;
        const ushort* An = Xb + (size_t)n * NSTR;  // slab0 = bf16 state for epilogue
        if (g + 1 < GN) {   // prefetch node n+1 (independent of current MFMAs)
            const ushort* An2 = An + NSTR;
#pragma unroll
            for (int kt = 0; kt < 11; ++kt) aN[kt] = *(const bf16x8*)(An2 + offA[kt]);
            aN[11] = (quad == 0) ? *(const bf16x8*)(An2 + off11) : zf;
        }
        f32x4 acc0 = {0.f, 0.f, 0.f, 0.f};
        f32x4 acc1 = {0.f, 0.f, 0.f, 0.f};
#pragma unroll
        for (int kt = 0; kt < 12; ++kt) {
            acc0 = __builtin_amdgcn_mfma_f32_16x16x32_bf16(aC[kt], w0[kt], acc0, 0, 0, 0);
            acc1 = __builtin_amdgcn_mfma_f32_16x16x32_bf16(aC[kt], w1[kt], acc1, 0, 0, 0);
        }
        // D: col = lane&15 (-> c0/c1), row b = quad*4 + reg
#pragma unroll
        for (int r = 0; r < 4; ++r) {
            int b = quad * 4 + r;
            float v0 = 1.f / (1.f + __expf(-(acc0[r] + bias0)));
            float v1 = 1.f / (1.f + __expf(-(acc1[r] + bias1)));
            if (wave < 2) {  // cols 0..63: r-gate -> xc state part (bf16, separate buffer)
                float s0 = bf2f(An[b * FP2 + 2 + c0]);   // state from slab0 (bf16, hot)
                float s1 = bf2f(An[b * FP2 + 2 + c1]);
                Xc[(size_t)n * SLABU + b * FP2 + 2 + c0] = f2bf(v0 * s0);
                Xc[(size_t)n * SLABU + b * FP2 + 2 + c1] = f2bf(v1 * s1);
            } else {         // cols 64..127: u-gate (fp32)
                U[(size_t)b * SN + n * HID + (c0 - HID)] = v0;
                U[(size_t)b * SN + n * HID + (c1 - HID)] = v1;
            }
        }
        if (g + 1 < GN) {
#pragma unroll
            for (int kt = 0; kt < 12; ++kt) aC[kt] = aN[kt];
        }
    }
}

// ---------------- candidate GEMM + tanh + GRU update + output ----------------
// Same node-loop software pipeline. U aliases out+OUTHALF -> NO __restrict__ on U/out.
// state stays fp32 here (direct output-path term).

__global__ __launch_bounds__(256, 2) void cand_mfma(const ushort* __restrict__ Xb,
                                                    const ushort* __restrict__ Xc,
                                                    const ushort* __restrict__ WcT,
                                                    const float* __restrict__ bc,
                                                    const float* __restrict__ state,
                                                    const float* U,
                                                    float* out) {
    int tid = threadIdx.x;
    int wave = tid >> 6, lane = tid & 63;
    int row = lane & 15, quad = lane >> 4;
    int c = wave * 16 + row;

    bf16x8 w[12];
#pragma unroll
    for (int kt = 0; kt < 12; ++kt)
        w[kt] = *(const bf16x8*)(WcT + (size_t)c * KP2 + kt * 32 + quad * 8);
    float bias = bc[c];

    int offA[11];
#pragma unroll
    for (int kt = 0; kt < 11; ++kt) {
        int j = 4 * kt + quad;
        int m = j / 9;
        int f0 = 8 * (j - 9 * m);
        offA[kt] = m * SLABU + row * FP2 + f0;  // m==0 offsets are also Xc-relative
    }
    int off11 = 4 * SLABU + row * FP2 + 64;
    const bf16x8 zf = {0, 0, 0, 0, 0, 0, 0, 0};

    int nodeBase = blockIdx.x * GN;
    bf16x8 aC[12], aN[12];
    auto loadA = [&](int n, bf16x8* a) {
        const ushort* AnB = Xb + (size_t)n * NSTR;
        const ushort* AnC = Xc + (size_t)n * SLABU;
#pragma unroll
        for (int kt = 0; kt < 11; ++kt) {
            // kt 0,1: pure slab0 (Xc). kt 2: quad0 -> Xc, quads 1..3 -> Xb slab1. kt>=3: Xb.
            const ushort* bp = (kt < 2) ? AnC
                             : (kt == 2 ? (quad == 0 ? AnC : AnB) : AnB);
            a[kt] = *(const bf16x8*)(bp + offA[kt]);
        }
        a[11] = (quad == 0) ? *(const bf16x8*)(AnB + off11) : zf;
    };
    loadA(nodeBase, aC);
    for (int g = 0; g < GN; ++g) {
        int n = nodeBase + g;
        if (g + 1 < GN) loadA(n + 1, aN);
        f32x4 acc = {0.f, 0.f, 0.f, 0.f};
#pragma unroll
        for (int kt = 0; kt < 12; ++kt)
            acc = __builtin_amdgcn_mfma_f32_16x16x32_bf16(aC[kt], w[kt], acc, 0, 0, 0);
#pragma unroll
        for (int r = 0; r < 4; ++r) {
            int b = quad * 4 + r;
            float pre = acc[r] + bias;
            float cv = 1.f - 2.f / (__expf(2.f * pre) + 1.f);  // tanh
            size_t idx = (size_t)b * SN + n * HID + c;
            float uv = U[idx];       // read BEFORE the aliased write below
            float s = state[idx];
            float ns = uv * s + (1.f - uv) * cv;
            out[idx] = ns;
            out[OUTHALF + idx] = ns; // overwrites U[idx] (same thread, after read)
        }
        if (g + 1 < GN) {
#pragma unroll
            for (int kt = 0; kt < 12; ++kt) aC[kt] = aN[kt];
        }
    }
}

// ---------------- launch ----------------

extern "C" void kernel_launch(void* const* d_in, const int* in_sizes, int n_in,
                              void* d_out, int out_size, void* d_ws, size_t ws_size,
                              hipStream_t stream) {
    const float* inputs = (const float*)d_in[0];
    const float* state  = (const float*)d_in[1];
    const int*   esrc   = (const int*)d_in[2];
    const int*   edst   = (const int*)d_in[3];
    const float* v1     = (const float*)d_in[4];
    const float* v2     = (const float*)d_in[5];
    const float* Wg     = (const float*)d_in[6];
    const float* bg     = (const float*)d_in[7];
    const float* Wc     = (const float*)d_in[8];
    const float* bc     = (const float*)d_in[9];
    float* out = (float*)d_out;

    char* ws = (char*)d_ws;
    size_t off = 0;
    auto alloc = [&](size_t bytes) -> void* {
        void* p = ws + off;
        off += (bytes + 255) & ~(size_t)255;
        return p;
    };
    ushort* Xb     = (ushort*)alloc((size_t)NNODES * NSTR * 2);   // 94.4 MB [n][m][b][72]
    ushort* Xc     = (ushort*)alloc((size_t)NNODES * SLABU * 2);  // 18.9 MB xc slab0
    ushort* WgT    = (ushort*)alloc((size_t)128 * KP2 * 2);
    ushort* WcT    = (ushort*)alloc((size_t)64 * KP2 * 2);
    int*   counts1 = (int*)alloc(NNODES * 4);
    int*   counts2 = (int*)alloc(NNODES * 4);
    int*   rowptr1 = (int*)alloc((NNODES + 1) * 4);
    int*   rowptr2 = (int*)alloc((NNODES + 1) * 4);
    int*   cursor1 = (int*)alloc(NNODES * 4);
    int*   cursor2 = (int*)alloc(NNODES * 4);
    int*   cols1   = (int*)alloc(NEDGE * 4);
    int*   cols2   = (int*)alloc(NEDGE * 4);
    float* valsC1  = (float*)alloc(NEDGE * 4);
    float* valsC2  = (float*)alloc(NEDGE * 4);

    // U scratch lives in the second output copy (dead until cand epilogue)
    float* U = out + OUTHALF;

    uint4* Xb4 = (uint4*)Xb;
    uint4* Xc4 = (uint4*)Xc;
    auto slab = [&](int m) { return Xb4 + (size_t)m * 144; };  // slab m base, node stride 720

    // CSR build: counts1/counts2 are adjacent 256-aligned blocks -> one memset
    hipMemsetAsync(counts1, 0, (size_t)2 * NNODES * 4, stream);
    hist_kernel<<<(NEDGE + 255) / 256, 256, 0, stream>>>(esrc, edst, counts1, counts2);
    scan_kernel<<<2, 1024, 0, stream>>>(counts1, counts2, rowptr1, rowptr2, cursor1, cursor2);
    scatter_kernel<<<(NEDGE + 255) / 256, 256, 0, stream>>>(esrc, edst, v1, v2,
                                                            cursor1, cursor2,
                                                            cols1, valsC1, cols2, valsC2);

    // fused weight-convert + x0-build (independent work, one dispatch)
    prep_kernel<<<CWB + BXB, 256, 0, stream>>>(Wg, Wc, WgT, WcT,
                                               inputs, state, (uint*)Xb, (uint*)Xc);

    // diff_conv #1 diffusion: both graphs per dispatch (dual)
    spmm_dual<<<2 * NNODES, 128, 0, stream>>>(rowptr1, cols1, valsC1, slab(0),
                                              rowptr2, cols2, valsC2, slab(0), NSTR4,
                                              slab(0), NSTR4, slab(1), slab(3), NSTR4,
                                              1.f, 0.f);
    spmm_dual<<<2 * NNODES, 128, 0, stream>>>(rowptr1, cols1, valsC1, slab(1),
                                              rowptr2, cols2, valsC2, slab(3), NSTR4,
                                              slab(0), NSTR4, slab(2), slab(4), NSTR4,
                                              2.f, -1.f);

    // gate GEMM + sigmoid; writes U (in d_out scratch) and xc slab0 (r*state) into Xc
    gate_mfma<<<NNODES / GN, 256, 0, stream>>>(Xb, WgT, bg, U, Xc);

    // diff_conv #2 diffusion on xc (x0 := Xc, node stride 144 uint4)
    spmm_dual<<<2 * NNODES, 128, 0, stream>>>(rowptr1, cols1, valsC1, Xc4,
                                              rowptr2, cols2, valsC2, Xc4, XCS4,
                                              Xc4, XCS4, slab(1), slab(3), NSTR4,
                                              1.f, 0.f);
    spmm_dual<<<2 * NNODES, 128, 0, stream>>>(rowptr1, cols1, valsC1, slab(1),
                                              rowptr2, cols2, valsC2, slab(3), NSTR4,
                                              Xc4, XCS4, slab(2), slab(4), NSTR4,
                                              2.f, -1.f);

    // candidate GEMM + tanh + GRU update + duplicated output
    cand_mfma<<<NNODES / GN, 256, 0, stream>>>(Xb, Xc, WcT, bc, state, U, out);
}

// Round 17
// 529.917 us; speedup vs baseline: 1.0875x; 1.0464x over previous
//
#include <hip/hip_runtime.h>
#include <hip/hip_fp8.h>
#include <cstddef>
#include <cstdint>

#define NNODES 8192
#define BATCH  16
#define HID    64
#define NEDGE  131072
#define SN     524288   // NNODES * HID (per-batch state stride)
#define OUTHALF 8388608 // BATCH * SN
#define FP2    72       // padded per-slab feature dim (66 real + 6 zero); 72 = 9*8
#define SLABU  1152     // ushorts per (node, slab) = 16*72
#define NSTR   5760     // ushorts per node = 5*SLABU
#define NSTR4  720      // uint4 per node in Xb (5760 ushorts / 8 per uint4)
#define XCS4   144      // uint4 per node in Xc (slab0-only buffer, 1152/8)
#define KP2    384      // padded K' = 12 k-tiles of 32 (360 real + 24 zero)
#define GN     8        // nodes per GEMM block
#define CWB    288      // convert_w blocks inside prep_kernel (192*KP2/256)
#define BXB    18432    // build_x0 blocks inside prep_kernel (NNODES*BATCH*36/256)
#define FRB    9437184  // fp8 region bytes: NNODES * 1152 (one slab mirror)

typedef __attribute__((ext_vector_type(8))) short bf16x8;
typedef __attribute__((ext_vector_type(4))) float f32x4;

static __device__ __forceinline__ float bf2f(ushort u) {
    union { uint32_t i; float f; } c; c.i = ((uint32_t)u) << 16; return c.f;
}
static __device__ __forceinline__ ushort f2bf(float f) {
    union { float f; uint32_t i; } c; c.f = f;
    uint32_t lsb = (c.i >> 16) & 1;
    return (ushort)((c.i + 0x7fffu + lsb) >> 16);
}
static __device__ __forceinline__ float fp8tof(uint b) {
    __hip_fp8_e4m3 h; h.__x = (__hip_fp8_storage_t)(b & 0xffu); return (float)h;
}
static __device__ __forceinline__ uint ftofp8(float f) {
    __hip_fp8_e4m3 h(f); return (uint)h.__x;
}

// ---------------- CSR construction ----------------

__global__ void hist_kernel(const int* __restrict__ src, const int* __restrict__ dst,
                            int* __restrict__ c1, int* __restrict__ c2) {
    int e = blockIdx.x * 256 + threadIdx.x;
    if (e < NEDGE) {
        atomicAdd(&c1[src[e]], 1);
        atomicAdd(&c2[dst[e]], 1);
    }
}

// Both CSR scans in ONE dispatch: block 0 -> graph 1, block 1 -> graph 2.
__global__ __launch_bounds__(1024) void scan_kernel(const int* __restrict__ counts1,
                                                    const int* __restrict__ counts2,
                                                    int* __restrict__ rowptr1,
                                                    int* __restrict__ rowptr2,
                                                    int* __restrict__ cursor1,
                                                    int* __restrict__ cursor2) {
    const int* counts = blockIdx.x ? counts2 : counts1;
    int* rowptr       = blockIdx.x ? rowptr2 : rowptr1;
    int* cursor       = blockIdx.x ? cursor2 : cursor1;
    __shared__ int sh[1024];
    int tid = threadIdx.x;
    int base = tid * 8;
    int local[8];
    int sum = 0;
#pragma unroll
    for (int j = 0; j < 8; ++j) { local[j] = counts[base + j]; sum += local[j]; }
    sh[tid] = sum;
    __syncthreads();
    for (int off = 1; off < 1024; off <<= 1) {
        int v = (tid >= off) ? sh[tid - off] : 0;
        __syncthreads();
        sh[tid] += v;
        __syncthreads();
    }
    int p = sh[tid] - sum;
#pragma unroll
    for (int j = 0; j < 8; ++j) {
        cursor[base + j] = p;
        p += local[j];
        rowptr[base + j + 1] = p;
    }
    if (tid == 0) rowptr[0] = 0;
}

__global__ void scatter_kernel(const int* __restrict__ src, const int* __restrict__ dst,
                               const float* __restrict__ v1, const float* __restrict__ v2,
                               int* __restrict__ cur1, int* __restrict__ cur2,
                               int* __restrict__ cols1, float* __restrict__ valsC1,
                               int* __restrict__ cols2, float* __restrict__ valsC2) {
    int e = blockIdx.x * 256 + threadIdx.x;
    if (e < NEDGE) {
        int r1 = src[e];
        int p1 = atomicAdd(&cur1[r1], 1);
        cols1[p1] = dst[e];
        valsC1[p1] = v1[e];
        int r2 = dst[e];
        int p2 = atomicAdd(&cur2[r2], 1);
        cols2[p2] = src[e];
        valsC2[p2] = v2[e];
    }
}

// -------- fused prep: convert_w (blocks [0,CWB)) + build_x0 (blocks [CWB,CWB+BXB)) --------
// build_x0 additionally writes the fp8 mirror of slab0 (gather source for hop A).

__global__ void prep_kernel(const float* __restrict__ Wg, const float* __restrict__ Wc,
                            ushort* __restrict__ WgT, ushort* __restrict__ WcT,
                            const float* __restrict__ inputs, const float* __restrict__ state,
                            uint* __restrict__ Xb_u, uint* __restrict__ Xc_u,
                            ushort* __restrict__ F0_us) {
    if (blockIdx.x < CWB) {
        int i = blockIdx.x * 256 + threadIdx.x;
        if (i >= 192 * KP2) return;
        int col = i / KP2, k2 = i - col * KP2;
        int m = k2 / FP2, f = k2 - m * FP2;
        bool valid = (m < 5) && (f < 66);
        int ko = f * 5 + m;
        if (col < 128) {
            WgT[col * KP2 + k2] = valid ? f2bf(Wg[ko * 128 + col]) : (ushort)0;
        } else {
            int c = col - 128;
            WcT[c * KP2 + k2] = valid ? f2bf(Wc[ko * 64 + c]) : (ushort)0;
        }
        return;
    }
    int t = (blockIdx.x - CWB) * 256 + threadIdx.x;
    if (t >= NNODES * BATCH * 36) return;
    int n = t / 576;           // 576 = 16*36 uints per node-slab
    int r = t - n * 576;       // b*36 + j
    int b = r / 36;
    int j = r - b * 36;
    int f0 = 2 * j;
    float v0 = 0.f, v1 = 0.f;
    uint val = 0;
    if (f0 == 0) {
        v0 = inputs[(size_t)b * (NNODES * 2) + n * 2 + 0];
        v1 = inputs[(size_t)b * (NNODES * 2) + n * 2 + 1];
        val = (uint)f2bf(v0) | ((uint)f2bf(v1) << 16);
    } else if (f0 < 66) {
        v0 = state[(size_t)b * SN + n * HID + (f0 - 2)];
        v1 = state[(size_t)b * SN + n * HID + (f0 - 1)];
        val = (uint)f2bf(v0) | ((uint)f2bf(v1) << 16);
    }
    Xb_u[(size_t)n * 2880 + r] = val;               // slab0 = first 576 uints of node
    if (f0 == 0 || f0 >= 66) Xc_u[t] = val;         // inputs + zero pads of xc slab0
    F0_us[t] = (ushort)(ftofp8(v0) | (ftofp8(v1) << 8));  // fp8 mirror of slab0
}

// ---------------- SPMM: fp8 gather, fp32 accumulate, bf16(+fp8) output, dual-graph ----------------
// r12 structure (8-wide predicated, 2 chunk-instructions/edge) but the gathered
// row is the 1152 B fp8 mirror -> HALF the 128 B lines per edge. The plateau was
// per-CU outstanding-line limited (r5/r8/r9/r12 converge at ~7.2 TB/s logical
// regardless of layout/occupancy/traffic), so halving lines ~halves time.

static __device__ __forceinline__ void fma8f8(float* acc, uint2 d, float v) {
    uint a = d.x, b = d.y;
    acc[0] += v * fp8tof(a);        acc[1] += v * fp8tof(a >> 8);
    acc[2] += v * fp8tof(a >> 16);  acc[3] += v * fp8tof(a >> 24);
    acc[4] += v * fp8tof(b);        acc[5] += v * fp8tof(b >> 8);
    acc[6] += v * fp8tof(b >> 16);  acc[7] += v * fp8tof(b >> 24);
}

static __device__ __forceinline__ void blend8(const float* acc, uint4 p,
                                              float alpha, float beta, float* o) {
    o[0] = alpha * acc[0] + beta * bf2f((ushort)(p.x));
    o[1] = alpha * acc[1] + beta * bf2f((ushort)(p.x >> 16));
    o[2] = alpha * acc[2] + beta * bf2f((ushort)(p.y));
    o[3] = alpha * acc[3] + beta * bf2f((ushort)(p.y >> 16));
    o[4] = alpha * acc[4] + beta * bf2f((ushort)(p.z));
    o[5] = alpha * acc[5] + beta * bf2f((ushort)(p.z >> 16));
    o[6] = alpha * acc[6] + beta * bf2f((ushort)(p.w));
    o[7] = alpha * acc[7] + beta * bf2f((ushort)(p.w >> 16));
}

static __device__ __forceinline__ uint4 packbf8(const float* o) {
    uint4 r;
    r.x = (uint32_t)f2bf(o[0]) | ((uint32_t)f2bf(o[1]) << 16);
    r.y = (uint32_t)f2bf(o[2]) | ((uint32_t)f2bf(o[3]) << 16);
    r.z = (uint32_t)f2bf(o[4]) | ((uint32_t)f2bf(o[5]) << 16);
    r.w = (uint32_t)f2bf(o[6]) | ((uint32_t)f2bf(o[7]) << 16);
    return r;
}

static __device__ __forceinline__ uint2 packf8(const float* o) {
    uint2 r;
    r.x = ftofp8(o[0]) | (ftofp8(o[1]) << 8) | (ftofp8(o[2]) << 16) | (ftofp8(o[3]) << 24);
    r.y = ftofp8(o[4]) | (ftofp8(o[5]) << 8) | (ftofp8(o[6]) << 16) | (ftofp8(o[7]) << 24);
    return r;
}

// fp8 row = 144 uint2 (1152 B) per (node, region); bf16 y row = 144 uint4.
// blocks [0,8192): graph 1; [8192,16384): graph 2.
__global__ __launch_bounds__(128) void spmm_dual(
        const int* __restrict__ rp1, const int* __restrict__ c1, const float* __restrict__ v1,
        const int* __restrict__ rp2, const int* __restrict__ c2, const float* __restrict__ v2,
        const uint2* __restrict__ xf1, const uint2* __restrict__ xf2,
        const uint4* __restrict__ xp, int ps,
        uint4* __restrict__ y1, uint4* __restrict__ y2, int ys,
        uint2* __restrict__ yf1, uint2* __restrict__ yf2,
        float alpha, float beta) {
    int bid = blockIdx.x;
    int half = bid >> 13;
    int n = bid & 8191;
    const int* rowptr = half ? rp2 : rp1;
    const int* cols   = half ? c2 : c1;
    const float* vals = half ? v2 : v1;
    const uint2* xf   = half ? xf2 : xf1;
    uint4* y          = half ? y2 : y1;
    uint2* yf         = half ? yf2 : yf1;

    int t = threadIdx.x;
    int s = rowptr[n], e = rowptr[n + 1];
    float a0[8] = {0, 0, 0, 0, 0, 0, 0, 0};
    float a1[8] = {0, 0, 0, 0, 0, 0, 0, 0};
    bool tail = t < 16;         // 144 chunks: t and (t<16 ? 128+t)
    int t2 = 128 + t;
    for (int i = s; i < e; i += 8) {
        int   c[8];
        float v[8];
#pragma unroll
        for (int k = 0; k < 8; ++k) {
            int ii = i + k;
            bool ok = ii < e;
            int idx = ok ? ii : s;      // clamp: row non-empty here (i<e)
            c[k] = cols[idx];
            v[k] = ok ? vals[idx] : 0.f;
        }
        uint2 d[8];
#pragma unroll
        for (int k = 0; k < 8; ++k) d[k] = xf[(size_t)c[k] * 144 + t];
        uint2 d2[8];
        if (tail) {
#pragma unroll
            for (int k = 0; k < 8; ++k) d2[k] = xf[(size_t)c[k] * 144 + t2];
        }
#pragma unroll
        for (int k = 0; k < 8; ++k) fma8f8(a0, d[k], v[k]);
        if (tail) {
#pragma unroll
            for (int k = 0; k < 8; ++k) fma8f8(a1, d2[k], v[k]);
        }
    }
    uint4* yb = y + (size_t)n * ys;
    const uint4* xpb = xp + (size_t)n * ps;
    float o[8];
    uint4 p0 = (beta != 0.f) ? xpb[t] : make_uint4(0, 0, 0, 0);
    blend8(a0, p0, alpha, beta, o);
    yb[t] = packbf8(o);
    if (yf) yf[(size_t)n * 144 + t] = packf8(o);
    if (tail) {
        uint4 p1 = (beta != 0.f) ? xpb[t2] : make_uint4(0, 0, 0, 0);
        blend8(a1, p1, alpha, beta, o);
        yb[t2] = packbf8(o);
        if (yf) yf[(size_t)n * 144 + t2] = packf8(o);
    }
}

// ---------------- gate GEMM: direct-global MFMA fragments + node-loop software pipeline ----------------
// r*state from Xb slab0 (bf16, L1/L2-hot). Also writes fp8 mirror of xc into F0.

__global__ __launch_bounds__(256, 2) void gate_mfma(const ushort* __restrict__ Xb,
                                                    const ushort* __restrict__ WgT,
                                                    const float* __restrict__ bg,
                                                    float* __restrict__ U,
                                                    ushort* __restrict__ Xc,
                                                    unsigned char* __restrict__ F0b) {
    int tid = threadIdx.x;
    int wave = tid >> 6, lane = tid & 63;
    int row = lane & 15, quad = lane >> 4;
    int c0 = wave * 32 + row;
    int c1 = c0 + 16;

    bf16x8 w0[12], w1[12];
#pragma unroll
    for (int kt = 0; kt < 12; ++kt) {
        w0[kt] = *(const bf16x8*)(WgT + (size_t)c0 * KP2 + kt * 32 + quad * 8);
        w1[kt] = *(const bf16x8*)(WgT + (size_t)c1 * KP2 + kt * 32 + quad * 8);
    }
    float bias0 = bg[c0], bias1 = bg[c1];

    int offA[11];
#pragma unroll
    for (int kt = 0; kt < 11; ++kt) {
        int j = 4 * kt + quad;
        int m = j / 9;
        int f0 = 8 * (j - 9 * m);
        offA[kt] = m * SLABU + row * FP2 + f0;
    }
    int off11 = 4 * SLABU + row * FP2 + 64;  // kt=11, quad 0 only (k' 352..359)
    const bf16x8 zf = {0, 0, 0, 0, 0, 0, 0, 0};

    int nodeBase = blockIdx.x * GN;
    bf16x8 aC[12], aN[12];
    {   // prologue: node nodeBase
        const ushort* An = Xb + (size_t)nodeBase * NSTR;
#pragma unroll
        for (int kt = 0; kt < 11; ++kt) aC[kt] = *(const bf16x8*)(An + offA[kt]);
        aC[11] = (quad == 0) ? *(const bf16x8*)(An + off11) : zf;
    }
    for (int g = 0; g < GN; ++g) {
        int n = nodeBase + g;
        const ushort* An = Xb + (size_t)n * NSTR;  // slab0 = bf16 state for epilogue
        if (g + 1 < GN) {   // prefetch node n+1 (independent of current MFMAs)
            const ushort* An2 = An + NSTR;
#pragma unroll
            for (int kt = 0; kt < 11; ++kt) aN[kt] = *(const bf16x8*)(An2 + offA[kt]);
            aN[11] = (quad == 0) ? *(const bf16x8*)(An2 + off11) : zf;
        }
        f32x4 acc0 = {0.f, 0.f, 0.f, 0.f};
        f32x4 acc1 = {0.f, 0.f, 0.f, 0.f};
#pragma unroll
        for (int kt = 0; kt < 12; ++kt) {
            acc0 = __builtin_amdgcn_mfma_f32_16x16x32_bf16(aC[kt], w0[kt], acc0, 0, 0, 0);
            acc1 = __builtin_amdgcn_mfma_f32_16x16x32_bf16(aC[kt], w1[kt], acc1, 0, 0, 0);
        }
        // D: col = lane&15 (-> c0/c1), row b = quad*4 + reg
#pragma unroll
        for (int r = 0; r < 4; ++r) {
            int b = quad * 4 + r;
            float v0 = 1.f / (1.f + __expf(-(acc0[r] + bias0)));
            float v1 = 1.f / (1.f + __expf(-(acc1[r] + bias1)));
            if (wave < 2) {  // cols 0..63: r-gate -> xc state part (bf16 + fp8 mirror)
                float s0 = bf2f(An[b * FP2 + 2 + c0]);   // state from slab0 (bf16, hot)
                float s1 = bf2f(An[b * FP2 + 2 + c1]);
                float x0v = v0 * s0, x1v = v1 * s1;
                Xc[(size_t)n * SLABU + b * FP2 + 2 + c0] = f2bf(x0v);
                Xc[(size_t)n * SLABU + b * FP2 + 2 + c1] = f2bf(x1v);
                F0b[(size_t)n * 1152 + b * FP2 + 2 + c0] = (unsigned char)ftofp8(x0v);
                F0b[(size_t)n * 1152 + b * FP2 + 2 + c1] = (unsigned char)ftofp8(x1v);
            } else {         // cols 64..127: u-gate (fp32)
                U[(size_t)b * SN + n * HID + (c0 - HID)] = v0;
                U[(size_t)b * SN + n * HID + (c1 - HID)] = v1;
            }
        }
        if (g + 1 < GN) {
#pragma unroll
            for (int kt = 0; kt < 12; ++kt) aC[kt] = aN[kt];
        }
    }
}

// ---------------- candidate GEMM + tanh + GRU update + output ----------------
// Same node-loop software pipeline. U aliases out+OUTHALF -> NO __restrict__ on U/out.
// cand's stores also overwrite the (now-dead) fp8 regions at the front of d_out.

__global__ __launch_bounds__(256, 2) void cand_mfma(const ushort* __restrict__ Xb,
                                                    const ushort* __restrict__ Xc,
                                                    const ushort* __restrict__ WcT,
                                                    const float* __restrict__ bc,
                                                    const float* __restrict__ state,
                                                    const float* U,
                                                    float* out) {
    int tid = threadIdx.x;
    int wave = tid >> 6, lane = tid & 63;
    int row = lane & 15, quad = lane >> 4;
    int c = wave * 16 + row;

    bf16x8 w[12];
#pragma unroll
    for (int kt = 0; kt < 12; ++kt)
        w[kt] = *(const bf16x8*)(WcT + (size_t)c * KP2 + kt * 32 + quad * 8);
    float bias = bc[c];

    int offA[11];
#pragma unroll
    for (int kt = 0; kt < 11; ++kt) {
        int j = 4 * kt + quad;
        int m = j / 9;
        int f0 = 8 * (j - 9 * m);
        offA[kt] = m * SLABU + row * FP2 + f0;  // m==0 offsets are also Xc-relative
    }
    int off11 = 4 * SLABU + row * FP2 + 64;
    const bf16x8 zf = {0, 0, 0, 0, 0, 0, 0, 0};

    int nodeBase = blockIdx.x * GN;
    bf16x8 aC[12], aN[12];
    auto loadA = [&](int n, bf16x8* a) {
        const ushort* AnB = Xb + (size_t)n * NSTR;
        const ushort* AnC = Xc + (size_t)n * SLABU;
#pragma unroll
        for (int kt = 0; kt < 11; ++kt) {
            // kt 0,1: pure slab0 (Xc). kt 2: quad0 -> Xc, quads 1..3 -> Xb slab1. kt>=3: Xb.
            const ushort* bp = (kt < 2) ? AnC
                             : (kt == 2 ? (quad == 0 ? AnC : AnB) : AnB);
            a[kt] = *(const bf16x8*)(bp + offA[kt]);
        }
        a[11] = (quad == 0) ? *(const bf16x8*)(AnB + off11) : zf;
    };
    loadA(nodeBase, aC);
    for (int g = 0; g < GN; ++g) {
        int n = nodeBase + g;
        if (g + 1 < GN) loadA(n + 1, aN);
        f32x4 acc = {0.f, 0.f, 0.f, 0.f};
#pragma unroll
        for (int kt = 0; kt < 12; ++kt)
            acc = __builtin_amdgcn_mfma_f32_16x16x32_bf16(aC[kt], w[kt], acc, 0, 0, 0);
#pragma unroll
        for (int r = 0; r < 4; ++r) {
            int b = quad * 4 + r;
            float pre = acc[r] + bias;
            float cv = 1.f - 2.f / (__expf(2.f * pre) + 1.f);  // tanh
            size_t idx = (size_t)b * SN + n * HID + c;
            float uv = U[idx];       // read BEFORE the aliased write below
            float s = state[idx];
            float ns = uv * s + (1.f - uv) * cv;
            out[idx] = ns;
            out[OUTHALF + idx] = ns; // overwrites U[idx] (same thread, after read)
        }
        if (g + 1 < GN) {
#pragma unroll
            for (int kt = 0; kt < 12; ++kt) aC[kt] = aN[kt];
        }
    }
}

// ---------------- launch ----------------

extern "C" void kernel_launch(void* const* d_in, const int* in_sizes, int n_in,
                              void* d_out, int out_size, void* d_ws, size_t ws_size,
                              hipStream_t stream) {
    const float* inputs = (const float*)d_in[0];
    const float* state  = (const float*)d_in[1];
    const int*   esrc   = (const int*)d_in[2];
    const int*   edst   = (const int*)d_in[3];
    const float* v1     = (const float*)d_in[4];
    const float* v2     = (const float*)d_in[5];
    const float* Wg     = (const float*)d_in[6];
    const float* bg     = (const float*)d_in[7];
    const float* Wc     = (const float*)d_in[8];
    const float* bc     = (const float*)d_in[9];
    float* out = (float*)d_out;

    char* ws = (char*)d_ws;
    size_t off = 0;
    auto alloc = [&](size_t bytes) -> void* {
        void* p = ws + off;
        off += (bytes + 255) & ~(size_t)255;
        return p;
    };
    ushort* Xb     = (ushort*)alloc((size_t)NNODES * NSTR * 2);   // 94.4 MB [n][m][b][72]
    ushort* Xc     = (ushort*)alloc((size_t)NNODES * SLABU * 2);  // 18.9 MB xc slab0
    ushort* WgT    = (ushort*)alloc((size_t)128 * KP2 * 2);
    ushort* WcT    = (ushort*)alloc((size_t)64 * KP2 * 2);
    int*   counts1 = (int*)alloc(NNODES * 4);
    int*   counts2 = (int*)alloc(NNODES * 4);
    int*   rowptr1 = (int*)alloc((NNODES + 1) * 4);
    int*   rowptr2 = (int*)alloc((NNODES + 1) * 4);
    int*   cursor1 = (int*)alloc(NNODES * 4);
    int*   cursor2 = (int*)alloc(NNODES * 4);
    int*   cols1   = (int*)alloc(NEDGE * 4);
    int*   cols2   = (int*)alloc(NEDGE * 4);
    float* valsC1  = (float*)alloc(NEDGE * 4);
    float* valsC2  = (float*)alloc(NEDGE * 4);

    // U scratch lives in the second output copy (dead until cand epilogue)
    float* U = out + OUTHALF;
    // fp8 mirror regions live in the FIRST output copy (dead until cand epilogue):
    // F0 = slab0/xc mirror, F1/F2 = slab1/slab3 mirrors. 28.3 MB < 33.5 MB half.
    unsigned char* Fb = (unsigned char*)d_out;
    uint2* F0 = (uint2*)Fb;
    uint2* F1 = (uint2*)(Fb + (size_t)FRB);
    uint2* F2 = (uint2*)(Fb + (size_t)2 * FRB);

    uint4* Xb4 = (uint4*)Xb;
    uint4* Xc4 = (uint4*)Xc;
    auto slab = [&](int m) { return Xb4 + (size_t)m * 144; };  // slab m base, node stride 720

    // CSR build: counts1/counts2 are adjacent 256-aligned blocks -> one memset
    hipMemsetAsync(counts1, 0, (size_t)2 * NNODES * 4, stream);
    hist_kernel<<<(NEDGE + 255) / 256, 256, 0, stream>>>(esrc, edst, counts1, counts2);
    scan_kernel<<<2, 1024, 0, stream>>>(counts1, counts2, rowptr1, rowptr2, cursor1, cursor2);
    scatter_kernel<<<(NEDGE + 255) / 256, 256, 0, stream>>>(esrc, edst, v1, v2,
                                                            cursor1, cursor2,
                                                            cols1, valsC1, cols2, valsC2);

    // fused weight-convert + x0-build (+ fp8 slab0 mirror)
    prep_kernel<<<CWB + BXB, 256, 0, stream>>>(Wg, Wc, WgT, WcT,
                                               inputs, state, (uint*)Xb, (uint*)Xc,
                                               (ushort*)F0);

    // diff_conv #1: hop A gathers fp8 slab0 -> slabs 1,3 (bf16 + fp8 mirrors)
    spmm_dual<<<2 * NNODES, 128, 0, stream>>>(rowptr1, cols1, valsC1,
                                              rowptr2, cols2, valsC2,
                                              F0, F0, slab(0), NSTR4,
                                              slab(1), slab(3), NSTR4,
                                              F1, F2, 1.f, 0.f);
    // hop B gathers fp8 slabs 1,3 -> slabs 2,4 (bf16 only)
    spmm_dual<<<2 * NNODES, 128, 0, stream>>>(rowptr1, cols1, valsC1,
                                              rowptr2, cols2, valsC2,
                                              F1, F2, slab(0), NSTR4,
                                              slab(2), slab(4), NSTR4,
                                              nullptr, nullptr, 2.f, -1.f);

    // gate GEMM + sigmoid; writes U, Xc (bf16) and F0 state-part (fp8 xc mirror)
    gate_mfma<<<NNODES / GN, 256, 0, stream>>>(Xb, WgT, bg, U, Xc, Fb);

    // diff_conv #2 on xc: hop A gathers fp8 xc (F0) -> slabs 1,3 + fp8 mirrors
    spmm_dual<<<2 * NNODES, 128, 0, stream>>>(rowptr1, cols1, valsC1,
                                              rowptr2, cols2, valsC2,
                                              F0, F0, Xc4, XCS4,
                                              slab(1), slab(3), NSTR4,
                                              F1, F2, 1.f, 0.f);
    spmm_dual<<<2 * NNODES, 128, 0, stream>>>(rowptr1, cols1, valsC1,
                                              rowptr2, cols2, valsC2,
                                              F1, F2, Xc4, XCS4,
                                              slab(2), slab(4), NSTR4,
                                              nullptr, nullptr, 2.f, -1.f);

    // candidate GEMM + tanh + GRU update + duplicated output
    cand_mfma<<<NNODES / GN, 256, 0, stream>>>(Xb, Xc, WcT, bc, state, U, out);
}